// Round 4
// baseline (357.688 us; speedup 1.0000x reference)
//
#include <hip/hip_runtime.h>
#include <math.h>

#define NN 10000
#define BB 4
#define EE 160000
#define CC 64
#define CE 16

// ---- workspace layout (bytes) ----
static constexpr size_t OFF_XPA    = 0;          // float[NN*BB*CC]
static constexpr size_t OFF_XPB    = 10240000;   // float[NN*BB*CC]
static constexpr size_t OFF_SA     = 20480000;   // float[NN*BB]
static constexpr size_t OFF_SB     = 20640000;   // float[NN*BB]
static constexpr size_t OFF_VECS   = 20800000;   // float[288]
static constexpr size_t OFF_COUNTS = 20801280;   // int[NN]
static constexpr size_t OFF_CURSOR = 20841280;   // int[NN]
static constexpr size_t OFF_OFFS   = 20881280;   // int[NN+1]
static constexpr size_t OFF_RECS   = 20921344;   // int2[EE]   (1.28 MB)
static constexpr size_t OFF_ATT    = 22201344;   // float4[EE] (2.56 MB)
static constexpr size_t OFF_SE12   = 24761344;   // float2[EE] (1.28 MB)
static constexpr size_t OFF_ORDER  = 26041344;   // int[NN]    -> total ~26.1 MB

__device__ __forceinline__ float sigmoidf_(float x) {
    // v_rcp_f32 (~1ulp) instead of IEEE divide; validated absmax-identical r1-r3
    return __builtin_amdgcn_rcpf(1.0f + __expf(-x));
}

// histogram of dst + (block 0) fold q@aw_q, k@aw_k, w_e@aw_e for both layers
__global__ void hist_vecs_kernel(const int* __restrict__ ei, int* __restrict__ counts,
                                 const float* __restrict__ q1, const float* __restrict__ k1,
                                 const float* __restrict__ aw1, const float* __restrict__ we1,
                                 const float* __restrict__ q2, const float* __restrict__ k2,
                                 const float* __restrict__ aw2, const float* __restrict__ we2,
                                 float* __restrict__ vecs) {
    int e = blockIdx.x * blockDim.x + threadIdx.x;
    if (e < EE) atomicAdd(&counts[ei[EE + e]], 1);
    if (blockIdx.x == 0) {
        int t = threadIdx.x;
        if (t < 64) {
            float a = 0.f, b = 0.f, c = 0.f, d = 0.f;
            for (int j = 0; j < 64; ++j) {
                a = fmaf(q1[t * 64 + j], aw1[j], a);
                b = fmaf(k1[t * 64 + j], aw1[64 + j], b);
                c = fmaf(q2[t * 64 + j], aw2[j], c);
                d = fmaf(k2[t * 64 + j], aw2[64 + j], d);
            }
            vecs[t] = a; vecs[64 + t] = b; vecs[144 + t] = c; vecs[208 + t] = d;
        }
        if (t < 16) {
            float a = 0.f, b = 0.f;
            for (int j = 0; j < 64; ++j) {
                a = fmaf(we1[t * 64 + j], aw1[128 + j], a);
                b = fmaf(we2[t * 64 + j], aw2[128 + j], b);
            }
            vecs[128 + t] = a; vecs[272 + t] = b;
        }
    }
}

// single-block: exclusive scan of counts -> offs, THEN counting-sort nodes by
// degree descending -> order[] (LPT schedule for conv_out). One launch.
__global__ __launch_bounds__(1024) void scan_order_kernel(const int* __restrict__ counts,
                                                          int* __restrict__ offs,
                                                          int* __restrict__ order) {
    __shared__ int hist[1024];
    __shared__ int cur[1024];
    __shared__ int startb[1024];
    __shared__ int wsum[16];
    int t = threadIdx.x;
    hist[t] = 0; cur[t] = 0;
    int lane = t & 63, wid = t >> 6;
    // ---- phase 1: exclusive scan ----
    int v[10];
    int s = 0;
    #pragma unroll
    for (int j = 0; j < 10; ++j) {
        int i = t * 10 + j;
        v[j] = (i < NN) ? counts[i] : 0;
        s += v[j];
    }
    int ps = s;
    #pragma unroll
    for (int off = 1; off < 64; off <<= 1) {
        int u = __shfl_up(ps, off, 64);
        if (lane >= off) ps += u;
    }
    if (lane == 63) wsum[wid] = ps;
    __syncthreads();   // also covers hist/cur zero-init
    int wbase = 0;
    for (int w = 0; w < wid; ++w) wbase += wsum[w];
    int tb = wbase + ps - s;  // exclusive prefix
    #pragma unroll
    for (int j = 0; j < 10; ++j) {
        int i = t * 10 + j;
        if (i < NN) offs[i] = tb;
        tb += v[j];
    }
    if (t == 1023) offs[NN] = tb;
    // ---- phase 2: degree histogram ----
    #pragma unroll
    for (int j = 0; j < 10; ++j) {
        int i = t * 10 + j;
        if (i < NN) {
            int d = v[j] > 1023 ? 1023 : v[j];
            atomicAdd(&hist[d], 1);
        }
    }
    __syncthreads();
    // ---- phase 3: suffix sums (descending bins) ----
    int r = 1023 - t;
    int hv = hist[r];
    int ps2 = hv;
    #pragma unroll
    for (int off = 1; off < 64; off <<= 1) {
        int u = __shfl_up(ps2, off, 64);
        if (lane >= off) ps2 += u;
    }
    if (lane == 63) wsum[wid] = ps2;
    __syncthreads();
    int wb2 = 0;
    for (int w = 0; w < wid; ++w) wb2 += wsum[w];
    startb[r] = wb2 + ps2 - hv;
    __syncthreads();
    // ---- phase 4: scatter node ids ----
    #pragma unroll
    for (int j = 0; j < 10; ++j) {
        int i = t * 10 + j;
        if (i < NN) {
            int d = v[j] > 1023 ? 1023 : v[j];
            int pos = startb[d] + atomicAdd(&cur[d], 1);
            order[pos] = i;
        }
    }
}

// CSR scatter; also fold attr·(w_e@aw_e)+ab per edge for both layers -> se12[e]
__global__ __launch_bounds__(256) void scatter_kernel(
    const int* __restrict__ ei, const int* __restrict__ offs,
    int* __restrict__ cursor, const float* __restrict__ attr,
    const float* __restrict__ vecs, const float* __restrict__ ab1,
    const float* __restrict__ ab2, int2* __restrict__ recs,
    float2* __restrict__ se12) {
    int e = blockIdx.x * blockDim.x + threadIdx.x;
    if (e >= EE) return;
    int s = ei[e], d = ei[EE + e];
    const float4* ap = (const float4*)(attr + (size_t)e * CE);
    float4 a0 = ap[0], a1 = ap[1], a2 = ap[2], a3 = ap[3];
    const float* v1 = vecs + 128;
    const float* v2 = vecs + 272;
    float s1 = ab1[0], s2 = ab2[0];
    s1 = fmaf(a0.x, v1[0], s1);  s1 = fmaf(a0.y, v1[1], s1);
    s1 = fmaf(a0.z, v1[2], s1);  s1 = fmaf(a0.w, v1[3], s1);
    s1 = fmaf(a1.x, v1[4], s1);  s1 = fmaf(a1.y, v1[5], s1);
    s1 = fmaf(a1.z, v1[6], s1);  s1 = fmaf(a1.w, v1[7], s1);
    s1 = fmaf(a2.x, v1[8], s1);  s1 = fmaf(a2.y, v1[9], s1);
    s1 = fmaf(a2.z, v1[10], s1); s1 = fmaf(a2.w, v1[11], s1);
    s1 = fmaf(a3.x, v1[12], s1); s1 = fmaf(a3.y, v1[13], s1);
    s1 = fmaf(a3.z, v1[14], s1); s1 = fmaf(a3.w, v1[15], s1);
    s2 = fmaf(a0.x, v2[0], s2);  s2 = fmaf(a0.y, v2[1], s2);
    s2 = fmaf(a0.z, v2[2], s2);  s2 = fmaf(a0.w, v2[3], s2);
    s2 = fmaf(a1.x, v2[4], s2);  s2 = fmaf(a1.y, v2[5], s2);
    s2 = fmaf(a1.z, v2[6], s2);  s2 = fmaf(a1.w, v2[7], s2);
    s2 = fmaf(a2.x, v2[8], s2);  s2 = fmaf(a2.y, v2[9], s2);
    s2 = fmaf(a2.z, v2[10], s2); s2 = fmaf(a2.w, v2[11], s2);
    s2 = fmaf(a3.x, v2[12], s2); s2 = fmaf(a3.y, v2[13], s2);
    s2 = fmaf(a3.z, v2[14], s2); s2 = fmaf(a3.w, v2[15], s2);
    int p = atomicAdd(&cursor[d], 1);
    recs[offs[d] + p] = make_int2(s, e);
    se12[e] = make_float2(s1, s2);
}

// xp = x @ w_n ; sa = xp@qa ; sb = xp@ka.  One wave per node, 4 nodes/block.
// (round-0/2 proven version)
__global__ __launch_bounds__(256) void node_prep_kernel(
    const float* __restrict__ x, const float* __restrict__ w_n,
    const float* __restrict__ qa, const float* __restrict__ ka,
    float* __restrict__ xp, float* __restrict__ sa, float* __restrict__ sb) {
    __shared__ float w_sh[64 * 64];     // 16 KB
    __shared__ float x_sh[4 * BB * CC]; // 4 KB
    int t = threadIdx.x;
    for (int i = t; i < 64 * 64; i += 256) w_sh[i] = w_n[i];
    int node0 = blockIdx.x * 4;
    const float4* xg = (const float4*)(x + (size_t)node0 * BB * CC);
    ((float4*)x_sh)[t] = xg[t];
    __syncthreads();
    int wave = t >> 6, lane = t & 63;
    int node = node0 + wave;
    const float* xrow = x_sh + wave * BB * CC;
    float acc0 = 0.f, acc1 = 0.f, acc2 = 0.f, acc3 = 0.f;
    #pragma unroll 8
    for (int ci = 0; ci < 64; ++ci) {
        float w = w_sh[ci * 64 + lane];
        acc0 = fmaf(xrow[ci], w, acc0);
        acc1 = fmaf(xrow[64 + ci], w, acc1);
        acc2 = fmaf(xrow[128 + ci], w, acc2);
        acc3 = fmaf(xrow[192 + ci], w, acc3);
    }
    size_t obase = (size_t)node * BB * CC + lane;
    xp[obase] = acc0;
    xp[obase + 64] = acc1;
    xp[obase + 128] = acc2;
    xp[obase + 192] = acc3;
    float qv = qa[lane], kv = ka[lane];
    float ra0 = acc0 * qv, ra1 = acc1 * qv, ra2 = acc2 * qv, ra3 = acc3 * qv;
    float rb0 = acc0 * kv, rb1 = acc1 * kv, rb2 = acc2 * kv, rb3 = acc3 * kv;
    #pragma unroll
    for (int off = 32; off >= 1; off >>= 1) {
        ra0 += __shfl_xor(ra0, off, 64); ra1 += __shfl_xor(ra1, off, 64);
        ra2 += __shfl_xor(ra2, off, 64); ra3 += __shfl_xor(ra3, off, 64);
        rb0 += __shfl_xor(rb0, off, 64); rb1 += __shfl_xor(rb1, off, 64);
        rb2 += __shfl_xor(rb2, off, 64); rb3 += __shfl_xor(rb3, off, 64);
    }
    if (lane == 0) {
        sa[node * BB + 0] = ra0; sa[node * BB + 1] = ra1;
        sa[node * BB + 2] = ra2; sa[node * BB + 3] = ra3;
        sb[node * BB + 0] = rb0; sb[node * BB + 1] = rb1;
        sb[node * BB + 2] = rb2; sb[node * BB + 3] = rb3;
    }
}

// per-edge attention scalar: att4[e] = sigmoid(sa[src] + sb[dst] + se12[e])
__global__ __launch_bounds__(256) void att_kernel(
    const int* __restrict__ ei, const float2* __restrict__ se12,
    const float* __restrict__ sa, const float* __restrict__ sb,
    float4* __restrict__ att, int sel) {
    int e = blockIdx.x * blockDim.x + threadIdx.x;
    if (e >= EE) return;
    int s = ei[e], d = ei[EE + e];
    float2 se2 = se12[e];
    float se = sel ? se2.y : se2.x;
    float4 sas = *(const float4*)(sa + (size_t)s * BB);
    float4 sbn = *(const float4*)(sb + (size_t)d * BB);
    float4 r;
    r.x = sigmoidf_(sas.x + sbn.x + se);
    r.y = sigmoidf_(sas.y + sbn.y + se);
    r.z = sigmoidf_(sas.z + sbn.z + se);
    r.w = sigmoidf_(sas.w + sbn.w + se);
    att[e] = r;
}

// Per-node segment-max aggregation + output linear + residual + leaky_relu.
// TLP split: 2 waves per node, 2 batches per wave (bh = wave&1), 2 nodes/block.
// Grid 5000 blocks -> ~2x resident waves -> ~2x in-flight xp-row gathers.
// Edge-loop body and epilogue are the round-2 proven forms, halved per wave.
__global__ __launch_bounds__(256) void conv_out_kernel(
    const float* __restrict__ xp,      // [NN,BB,CC]
    const int2* __restrict__ recs,     // [EE] {src, e}
    const int* __restrict__ offs,      // [NN+1]
    const float* __restrict__ attr,    // [EE,CE]
    const float* __restrict__ w_e,     // [CE,CC]
    const float4* __restrict__ att,    // [EE]
    const float* __restrict__ ow,      // [2*CC,CC]
    const float* __restrict__ ob,      // [CC]
    const int* __restrict__ order,     // [NN] degree-descending node ids
    float* __restrict__ out) {         // [NN,BB,CC]
    __shared__ float aggr_sh[4][2 * CC];   // 2 KB (wave-private rows)
    __shared__ float xpn_sh[4][2 * CC];    // 2 KB
    int t = threadIdx.x;
    int wave = t >> 6, lane = t & 63;
    int bh = wave & 1;                          // batch half: batches {2bh, 2bh+1}
    int node = order[blockIdx.x * 2 + (wave >> 1)];

    float wec[CE];
    #pragma unroll
    for (int j = 0; j < CE; ++j) wec[j] = w_e[j * CC + lane];

    const float* xn = xp + (size_t)node * BB * CC + bh * 128 + lane;
    float xn0 = xn[0], xn1 = xn[64];

    int o0 = offs[node], o1 = offs[node + 1];
    float m0 = -INFINITY, m1 = -INFINITY;

    int i = o0;
    int2 rec = (i < o1) ? recs[i] : make_int2(0, 0);
    while (i < o1) {
        int2 cur = rec;
        ++i;
        if (i < o1) rec = recs[i];  // prefetch next
        int s = cur.x, e = cur.y;
        float2 at = ((const float2*)att)[2 * e + bh];
        const float4* ap = (const float4*)(attr + (size_t)e * CE);
        float4 a0 = ap[0], a1 = ap[1], a2 = ap[2], a3 = ap[3];
        float g = 0.f;
        g = fmaf(a0.x, wec[0], g);  g = fmaf(a0.y, wec[1], g);
        g = fmaf(a0.z, wec[2], g);  g = fmaf(a0.w, wec[3], g);
        g = fmaf(a1.x, wec[4], g);  g = fmaf(a1.y, wec[5], g);
        g = fmaf(a1.z, wec[6], g);  g = fmaf(a1.w, wec[7], g);
        g = fmaf(a2.x, wec[8], g);  g = fmaf(a2.y, wec[9], g);
        g = fmaf(a2.z, wec[10], g); g = fmaf(a2.w, wec[11], g);
        g = fmaf(a3.x, wec[12], g); g = fmaf(a3.y, wec[13], g);
        g = fmaf(a3.z, wec[14], g); g = fmaf(a3.w, wec[15], g);
        g = sigmoidf_(g);
        const float* xs = xp + (size_t)s * BB * CC + bh * 128 + lane;
        float x0 = xs[0], x1 = xs[64];
        m0 = fmaxf(m0, at.x * x0 * g);
        m1 = fmaxf(m1, at.y * x1 * g);
    }
    // empty segments -> 0
    m0 = (m0 == -INFINITY) ? 0.f : m0;
    m1 = (m1 == -INFINITY) ? 0.f : m1;

    float* ag = aggr_sh[wave];   // wave-private: no __syncthreads needed
    float* xq = xpn_sh[wave];
    ag[lane] = m0; ag[CC + lane] = m1;
    xq[lane] = xn0; xq[CC + lane] = xn1;
    asm volatile("s_waitcnt lgkmcnt(0)" ::: "memory");  // in-wave LDS RAW fence

    float o0f = 0.f, o1f = 0.f;
    #pragma unroll 4
    for (int ci = 0; ci < 64; ++ci) {
        float wa = ow[ci * 64 + lane];         // coalesced, L1/L2-resident
        float wb = ow[(64 + ci) * 64 + lane];
        o0f = fmaf(xq[ci], wa, o0f);
        o1f = fmaf(xq[CC + ci], wa, o1f);
        o0f = fmaf(ag[ci], wb, o0f);
        o1f = fmaf(ag[CC + ci], wb, o1f);
    }
    // out = xp + (concat([xp, aggr]) @ ow + ob), then leaky_relu(0.01)
    float obv = ob[lane];
    float r0 = xn0 + o0f + obv;
    float r1 = xn1 + o1f + obv;
    r0 = (r0 > 0.f) ? r0 : 0.01f * r0;
    r1 = (r1 > 0.f) ? r1 : 0.01f * r1;
    float* op = out + (size_t)node * BB * CC + bh * 128 + lane;
    op[0] = r0; op[64] = r1;
}

extern "C" void kernel_launch(void* const* d_in, const int* in_sizes, int n_in,
                              void* d_out, int out_size, void* d_ws, size_t ws_size,
                              hipStream_t stream) {
    const float* X    = (const float*)d_in[0];
    const int*   ei   = (const int*)d_in[1];
    const float* attr = (const float*)d_in[2];
    const float* w_n1 = (const float*)d_in[3];
    const float* w_e1 = (const float*)d_in[4];
    const float* q1   = (const float*)d_in[5];
    const float* k1   = (const float*)d_in[6];
    const float* aw1  = (const float*)d_in[7];
    const float* ab1  = (const float*)d_in[8];
    const float* ow1  = (const float*)d_in[9];
    const float* ob1  = (const float*)d_in[10];
    const float* w_n2 = (const float*)d_in[11];
    const float* w_e2 = (const float*)d_in[12];
    const float* q2   = (const float*)d_in[13];
    const float* k2   = (const float*)d_in[14];
    const float* aw2  = (const float*)d_in[15];
    const float* ab2  = (const float*)d_in[16];
    const float* ow2  = (const float*)d_in[17];
    const float* ob2  = (const float*)d_in[18];
    float* out = (float*)d_out;

    char* ws = (char*)d_ws;
    float*  xpA    = (float*)(ws + OFF_XPA);
    float*  xpB    = (float*)(ws + OFF_XPB);
    float*  sa     = (float*)(ws + OFF_SA);
    float*  sb     = (float*)(ws + OFF_SB);
    float*  vecs   = (float*)(ws + OFF_VECS);
    int*    counts = (int*)(ws + OFF_COUNTS);
    int*    cursor = (int*)(ws + OFF_CURSOR);
    int*    offs   = (int*)(ws + OFF_OFFS);
    int2*   recs   = (int2*)(ws + OFF_RECS);
    float4* att    = (float4*)(ws + OFF_ATT);
    float2* se12   = (float2*)(ws + OFF_SE12);
    int*    order  = (int*)(ws + OFF_ORDER);

    // CSR build (edge_index is layer-invariant)
    hipMemsetAsync(counts, 0, 2 * NN * sizeof(int), stream);  // counts + cursor
    hist_vecs_kernel<<<EE / 256, 256, 0, stream>>>(ei, counts, q1, k1, aw1, w_e1,
                                                   q2, k2, aw2, w_e2, vecs);
    scan_order_kernel<<<1, 1024, 0, stream>>>(counts, offs, order);
    scatter_kernel<<<EE / 256, 256, 0, stream>>>(ei, offs, cursor, attr, vecs,
                                                 ab1, ab2, recs, se12);
    // layer 1
    node_prep_kernel<<<NN / 4, 256, 0, stream>>>(X, w_n1, vecs + 0, vecs + 64, xpA, sa, sb);
    att_kernel<<<EE / 256, 256, 0, stream>>>(ei, se12, sa, sb, att, 0);
    conv_out_kernel<<<NN / 2, 256, 0, stream>>>(xpA, recs, offs, attr, w_e1, att,
                                                ow1, ob1, order, xpB);
    // layer 2
    node_prep_kernel<<<NN / 4, 256, 0, stream>>>(xpB, w_n2, vecs + 144, vecs + 208, xpA, sa, sb);
    att_kernel<<<EE / 256, 256, 0, stream>>>(ei, se12, sa, sb, att, 1);
    conv_out_kernel<<<NN / 2, 256, 0, stream>>>(xpA, recs, offs, attr, w_e2, att,
                                                ow2, ob2, order, out);
}

// Round 5
// 285.112 us; speedup vs baseline: 1.2546x; 1.2546x over previous
//
#include <hip/hip_runtime.h>
#include <math.h>

#define NN 10000
#define BB 4
#define EE 160000
#define CC 64
#define CE 16

// ---- workspace layout (bytes) ----
static constexpr size_t OFF_XPA    = 0;          // float[NN*BB*CC]
static constexpr size_t OFF_XPB    = 10240000;   // float[NN*BB*CC]
static constexpr size_t OFF_SA     = 20480000;   // float[NN*BB]
static constexpr size_t OFF_SB     = 20640000;   // float[NN*BB]
static constexpr size_t OFF_VECS   = 20800000;   // float[288]
static constexpr size_t OFF_COUNTS = 20801280;   // int[NN]
static constexpr size_t OFF_CURSOR = 20841280;   // int[NN]
static constexpr size_t OFF_OFFS   = 20881280;   // int[NN+1]
static constexpr size_t OFF_RECS   = 20921344;   // int2[EE]   (1.28 MB)
static constexpr size_t OFF_ATT    = 22201344;   // float4[EE] (2.56 MB)
static constexpr size_t OFF_SE12   = 24761344;   // float2[EE] (1.28 MB)
static constexpr size_t OFF_ORDER  = 26041344;   // int[NN]    -> total ~26.1 MB

__device__ __forceinline__ float sigmoidf_(float x) {
    // v_rcp_f32 (~1ulp) instead of IEEE divide; validated absmax-identical r1-r4
    return __builtin_amdgcn_rcpf(1.0f + __expf(-x));
}

// broadcast lane `l` (compile-time) of v to all lanes via v_readlane (SGPR path,
// NOT the LDS pipe -- ds_bpermute would recreate the LDS bottleneck)
__device__ __forceinline__ float bcast_(float v, int l) {
    return __uint_as_float(__builtin_amdgcn_readlane(__float_as_uint(v), l));
}

// histogram of dst + (block 0) fold q@aw_q, k@aw_k, w_e@aw_e for both layers
__global__ void hist_vecs_kernel(const int* __restrict__ ei, int* __restrict__ counts,
                                 const float* __restrict__ q1, const float* __restrict__ k1,
                                 const float* __restrict__ aw1, const float* __restrict__ we1,
                                 const float* __restrict__ q2, const float* __restrict__ k2,
                                 const float* __restrict__ aw2, const float* __restrict__ we2,
                                 float* __restrict__ vecs) {
    int e = blockIdx.x * blockDim.x + threadIdx.x;
    if (e < EE) atomicAdd(&counts[ei[EE + e]], 1);
    if (blockIdx.x == 0) {
        int t = threadIdx.x;
        if (t < 64) {
            float a = 0.f, b = 0.f, c = 0.f, d = 0.f;
            for (int j = 0; j < 64; ++j) {
                a = fmaf(q1[t * 64 + j], aw1[j], a);
                b = fmaf(k1[t * 64 + j], aw1[64 + j], b);
                c = fmaf(q2[t * 64 + j], aw2[j], c);
                d = fmaf(k2[t * 64 + j], aw2[64 + j], d);
            }
            vecs[t] = a; vecs[64 + t] = b; vecs[144 + t] = c; vecs[208 + t] = d;
        }
        if (t < 16) {
            float a = 0.f, b = 0.f;
            for (int j = 0; j < 64; ++j) {
                a = fmaf(we1[t * 64 + j], aw1[128 + j], a);
                b = fmaf(we2[t * 64 + j], aw2[128 + j], b);
            }
            vecs[128 + t] = a; vecs[272 + t] = b;
        }
    }
}

// single-block: exclusive scan of counts -> offs, THEN counting-sort nodes by
// degree descending -> order[] (LPT schedule for conv_out). One launch.
__global__ __launch_bounds__(1024) void scan_order_kernel(const int* __restrict__ counts,
                                                          int* __restrict__ offs,
                                                          int* __restrict__ order) {
    __shared__ int hist[1024];
    __shared__ int cur[1024];
    __shared__ int startb[1024];
    __shared__ int wsum[16];
    int t = threadIdx.x;
    hist[t] = 0; cur[t] = 0;
    int lane = t & 63, wid = t >> 6;
    // ---- phase 1: exclusive scan ----
    int v[10];
    int s = 0;
    #pragma unroll
    for (int j = 0; j < 10; ++j) {
        int i = t * 10 + j;
        v[j] = (i < NN) ? counts[i] : 0;
        s += v[j];
    }
    int ps = s;
    #pragma unroll
    for (int off = 1; off < 64; off <<= 1) {
        int u = __shfl_up(ps, off, 64);
        if (lane >= off) ps += u;
    }
    if (lane == 63) wsum[wid] = ps;
    __syncthreads();   // also covers hist/cur zero-init
    int wbase = 0;
    for (int w = 0; w < wid; ++w) wbase += wsum[w];
    int tb = wbase + ps - s;  // exclusive prefix
    #pragma unroll
    for (int j = 0; j < 10; ++j) {
        int i = t * 10 + j;
        if (i < NN) offs[i] = tb;
        tb += v[j];
    }
    if (t == 1023) offs[NN] = tb;
    // ---- phase 2: degree histogram ----
    #pragma unroll
    for (int j = 0; j < 10; ++j) {
        int i = t * 10 + j;
        if (i < NN) {
            int d = v[j] > 1023 ? 1023 : v[j];
            atomicAdd(&hist[d], 1);
        }
    }
    __syncthreads();
    // ---- phase 3: suffix sums (descending bins) ----
    int r = 1023 - t;
    int hv = hist[r];
    int ps2 = hv;
    #pragma unroll
    for (int off = 1; off < 64; off <<= 1) {
        int u = __shfl_up(ps2, off, 64);
        if (lane >= off) ps2 += u;
    }
    if (lane == 63) wsum[wid] = ps2;
    __syncthreads();
    int wb2 = 0;
    for (int w = 0; w < wid; ++w) wb2 += wsum[w];
    startb[r] = wb2 + ps2 - hv;
    __syncthreads();
    // ---- phase 4: scatter node ids ----
    #pragma unroll
    for (int j = 0; j < 10; ++j) {
        int i = t * 10 + j;
        if (i < NN) {
            int d = v[j] > 1023 ? 1023 : v[j];
            int pos = startb[d] + atomicAdd(&cur[d], 1);
            order[pos] = i;
        }
    }
}

// CSR scatter; also fold attr·(w_e@aw_e)+ab per edge for both layers -> se12[e]
__global__ __launch_bounds__(256) void scatter_kernel(
    const int* __restrict__ ei, const int* __restrict__ offs,
    int* __restrict__ cursor, const float* __restrict__ attr,
    const float* __restrict__ vecs, const float* __restrict__ ab1,
    const float* __restrict__ ab2, int2* __restrict__ recs,
    float2* __restrict__ se12) {
    int e = blockIdx.x * blockDim.x + threadIdx.x;
    if (e >= EE) return;
    int s = ei[e], d = ei[EE + e];
    const float4* ap = (const float4*)(attr + (size_t)e * CE);
    float4 a0 = ap[0], a1 = ap[1], a2 = ap[2], a3 = ap[3];
    const float* v1 = vecs + 128;
    const float* v2 = vecs + 272;
    float s1 = ab1[0], s2 = ab2[0];
    s1 = fmaf(a0.x, v1[0], s1);  s1 = fmaf(a0.y, v1[1], s1);
    s1 = fmaf(a0.z, v1[2], s1);  s1 = fmaf(a0.w, v1[3], s1);
    s1 = fmaf(a1.x, v1[4], s1);  s1 = fmaf(a1.y, v1[5], s1);
    s1 = fmaf(a1.z, v1[6], s1);  s1 = fmaf(a1.w, v1[7], s1);
    s1 = fmaf(a2.x, v1[8], s1);  s1 = fmaf(a2.y, v1[9], s1);
    s1 = fmaf(a2.z, v1[10], s1); s1 = fmaf(a2.w, v1[11], s1);
    s1 = fmaf(a3.x, v1[12], s1); s1 = fmaf(a3.y, v1[13], s1);
    s1 = fmaf(a3.z, v1[14], s1); s1 = fmaf(a3.w, v1[15], s1);
    s2 = fmaf(a0.x, v2[0], s2);  s2 = fmaf(a0.y, v2[1], s2);
    s2 = fmaf(a0.z, v2[2], s2);  s2 = fmaf(a0.w, v2[3], s2);
    s2 = fmaf(a1.x, v2[4], s2);  s2 = fmaf(a1.y, v2[5], s2);
    s2 = fmaf(a1.z, v2[6], s2);  s2 = fmaf(a1.w, v2[7], s2);
    s2 = fmaf(a2.x, v2[8], s2);  s2 = fmaf(a2.y, v2[9], s2);
    s2 = fmaf(a2.z, v2[10], s2); s2 = fmaf(a2.w, v2[11], s2);
    s2 = fmaf(a3.x, v2[12], s2); s2 = fmaf(a3.y, v2[13], s2);
    s2 = fmaf(a3.z, v2[14], s2); s2 = fmaf(a3.w, v2[15], s2);
    int p = atomicAdd(&cursor[d], 1);
    recs[offs[d] + p] = make_int2(s, e);
    se12[e] = make_float2(s1, s2);
}

// xp = x @ w_n ; sa = xp@qa ; sb = xp@ka.  One wave per node, 4 nodes/block.
// (round-0/2 proven version)
__global__ __launch_bounds__(256) void node_prep_kernel(
    const float* __restrict__ x, const float* __restrict__ w_n,
    const float* __restrict__ qa, const float* __restrict__ ka,
    float* __restrict__ xp, float* __restrict__ sa, float* __restrict__ sb) {
    __shared__ float w_sh[64 * 64];     // 16 KB
    __shared__ float x_sh[4 * BB * CC]; // 4 KB
    int t = threadIdx.x;
    for (int i = t; i < 64 * 64; i += 256) w_sh[i] = w_n[i];
    int node0 = blockIdx.x * 4;
    const float4* xg = (const float4*)(x + (size_t)node0 * BB * CC);
    ((float4*)x_sh)[t] = xg[t];
    __syncthreads();
    int wave = t >> 6, lane = t & 63;
    int node = node0 + wave;
    const float* xrow = x_sh + wave * BB * CC;
    float acc0 = 0.f, acc1 = 0.f, acc2 = 0.f, acc3 = 0.f;
    #pragma unroll 8
    for (int ci = 0; ci < 64; ++ci) {
        float w = w_sh[ci * 64 + lane];
        acc0 = fmaf(xrow[ci], w, acc0);
        acc1 = fmaf(xrow[64 + ci], w, acc1);
        acc2 = fmaf(xrow[128 + ci], w, acc2);
        acc3 = fmaf(xrow[192 + ci], w, acc3);
    }
    size_t obase = (size_t)node * BB * CC + lane;
    xp[obase] = acc0;
    xp[obase + 64] = acc1;
    xp[obase + 128] = acc2;
    xp[obase + 192] = acc3;
    float qv = qa[lane], kv = ka[lane];
    float ra0 = acc0 * qv, ra1 = acc1 * qv, ra2 = acc2 * qv, ra3 = acc3 * qv;
    float rb0 = acc0 * kv, rb1 = acc1 * kv, rb2 = acc2 * kv, rb3 = acc3 * kv;
    #pragma unroll
    for (int off = 32; off >= 1; off >>= 1) {
        ra0 += __shfl_xor(ra0, off, 64); ra1 += __shfl_xor(ra1, off, 64);
        ra2 += __shfl_xor(ra2, off, 64); ra3 += __shfl_xor(ra3, off, 64);
        rb0 += __shfl_xor(rb0, off, 64); rb1 += __shfl_xor(rb1, off, 64);
        rb2 += __shfl_xor(rb2, off, 64); rb3 += __shfl_xor(rb3, off, 64);
    }
    if (lane == 0) {
        sa[node * BB + 0] = ra0; sa[node * BB + 1] = ra1;
        sa[node * BB + 2] = ra2; sa[node * BB + 3] = ra3;
        sb[node * BB + 0] = rb0; sb[node * BB + 1] = rb1;
        sb[node * BB + 2] = rb2; sb[node * BB + 3] = rb3;
    }
}

// per-edge attention scalar: att4[e] = sigmoid(sa[src] + sb[dst] + se12[e])
__global__ __launch_bounds__(256) void att_kernel(
    const int* __restrict__ ei, const float2* __restrict__ se12,
    const float* __restrict__ sa, const float* __restrict__ sb,
    float4* __restrict__ att, int sel) {
    int e = blockIdx.x * blockDim.x + threadIdx.x;
    if (e >= EE) return;
    int s = ei[e], d = ei[EE + e];
    float2 se2 = se12[e];
    float se = sel ? se2.y : se2.x;
    float4 sas = *(const float4*)(sa + (size_t)s * BB);
    float4 sbn = *(const float4*)(sb + (size_t)d * BB);
    float4 r;
    r.x = sigmoidf_(sas.x + sbn.x + se);
    r.y = sigmoidf_(sas.y + sbn.y + se);
    r.z = sigmoidf_(sas.z + sbn.z + se);
    r.w = sigmoidf_(sas.w + sbn.w + se);
    att[e] = r;
}

// Per-node segment-max aggregation + output linear + residual + leaky_relu.
// One wave per node (lane = channel), 4 nodes/block, degree-sorted (LPT).
// Edge loop: exact round-2 proven form.  Epilogue: ZERO LDS -- the per-channel
// scalars xr[ci]/ar[ci] live in lane ci's registers; broadcast via v_readlane
// (SGPR operand path on the 4 per-SIMD VALU pipes) instead of 512 broadcast
// ds_read_b32 on the single per-CU LDS pipe (the r2 bottleneck: ~116k of 143k cy).
__global__ __launch_bounds__(256) void conv_out_kernel(
    const float* __restrict__ xp,      // [NN,BB,CC]
    const int2* __restrict__ recs,     // [EE] {src, e}
    const int* __restrict__ offs,      // [NN+1]
    const float* __restrict__ attr,    // [EE,CE]
    const float* __restrict__ w_e,     // [CE,CC]
    const float4* __restrict__ att,    // [EE]
    const float* __restrict__ ow,      // [2*CC,CC]
    const float* __restrict__ ob,      // [CC]
    const int* __restrict__ order,     // [NN] degree-descending node ids
    float* __restrict__ out) {         // [NN,BB,CC]
    int t = threadIdx.x;
    int wave = t >> 6, lane = t & 63;
    int node = order[blockIdx.x * 4 + wave];

    float wec[CE];
    #pragma unroll
    for (int j = 0; j < CE; ++j) wec[j] = w_e[j * CC + lane];

    const float* xn = xp + (size_t)node * BB * CC + lane;
    float xn0 = xn[0], xn1 = xn[64], xn2 = xn[128], xn3 = xn[192];

    int o0 = offs[node], o1 = offs[node + 1];
    float m0 = -INFINITY, m1 = -INFINITY, m2 = -INFINITY, m3 = -INFINITY;

    int i = o0;
    int2 rec = (i < o1) ? recs[i] : make_int2(0, 0);
    while (i < o1) {
        int2 cur = rec;
        ++i;
        if (i < o1) rec = recs[i];  // prefetch next
        int s = cur.x, e = cur.y;
        float4 at = att[e];
        const float4* ap = (const float4*)(attr + (size_t)e * CE);
        float4 a0 = ap[0], a1 = ap[1], a2 = ap[2], a3 = ap[3];
        float g = 0.f;
        g = fmaf(a0.x, wec[0], g);  g = fmaf(a0.y, wec[1], g);
        g = fmaf(a0.z, wec[2], g);  g = fmaf(a0.w, wec[3], g);
        g = fmaf(a1.x, wec[4], g);  g = fmaf(a1.y, wec[5], g);
        g = fmaf(a1.z, wec[6], g);  g = fmaf(a1.w, wec[7], g);
        g = fmaf(a2.x, wec[8], g);  g = fmaf(a2.y, wec[9], g);
        g = fmaf(a2.z, wec[10], g); g = fmaf(a2.w, wec[11], g);
        g = fmaf(a3.x, wec[12], g); g = fmaf(a3.y, wec[13], g);
        g = fmaf(a3.z, wec[14], g); g = fmaf(a3.w, wec[15], g);
        g = sigmoidf_(g);
        const float* xs = xp + (size_t)s * BB * CC + lane;
        float x0 = xs[0], x1 = xs[64], x2 = xs[128], x3 = xs[192];
        m0 = fmaxf(m0, at.x * x0 * g);
        m1 = fmaxf(m1, at.y * x1 * g);
        m2 = fmaxf(m2, at.z * x2 * g);
        m3 = fmaxf(m3, at.w * x3 * g);
    }
    // empty segments -> 0
    m0 = (m0 == -INFINITY) ? 0.f : m0;
    m1 = (m1 == -INFINITY) ? 0.f : m1;
    m2 = (m2 == -INFINITY) ? 0.f : m2;
    m3 = (m3 == -INFINITY) ? 0.f : m3;

    // ---- epilogue: out = xp + concat([xp, aggr]) @ ow + ob, leaky_relu ----
    // lane = output channel; per ci: 2 coalesced ow loads + 8 readlane + 8 FMA
    float o0f = 0.f, o1f = 0.f, o2f = 0.f, o3f = 0.f;
    #pragma unroll
    for (int ci = 0; ci < 64; ++ci) {
        float wa = ow[ci * 64 + lane];         // coalesced, L1/L2-resident
        float wb = ow[(64 + ci) * 64 + lane];
        o0f = fmaf(bcast_(xn0, ci), wa, o0f);
        o1f = fmaf(bcast_(xn1, ci), wa, o1f);
        o2f = fmaf(bcast_(xn2, ci), wa, o2f);
        o3f = fmaf(bcast_(xn3, ci), wa, o3f);
        o0f = fmaf(bcast_(m0, ci), wb, o0f);
        o1f = fmaf(bcast_(m1, ci), wb, o1f);
        o2f = fmaf(bcast_(m2, ci), wb, o2f);
        o3f = fmaf(bcast_(m3, ci), wb, o3f);
    }
    float obv = ob[lane];
    float r0 = xn0 + o0f + obv;
    float r1 = xn1 + o1f + obv;
    float r2 = xn2 + o2f + obv;
    float r3 = xn3 + o3f + obv;
    r0 = (r0 > 0.f) ? r0 : 0.01f * r0;
    r1 = (r1 > 0.f) ? r1 : 0.01f * r1;
    r2 = (r2 > 0.f) ? r2 : 0.01f * r2;
    r3 = (r3 > 0.f) ? r3 : 0.01f * r3;
    float* op = out + (size_t)node * BB * CC + lane;
    op[0] = r0; op[64] = r1; op[128] = r2; op[192] = r3;
}

extern "C" void kernel_launch(void* const* d_in, const int* in_sizes, int n_in,
                              void* d_out, int out_size, void* d_ws, size_t ws_size,
                              hipStream_t stream) {
    const float* X    = (const float*)d_in[0];
    const int*   ei   = (const int*)d_in[1];
    const float* attr = (const float*)d_in[2];
    const float* w_n1 = (const float*)d_in[3];
    const float* w_e1 = (const float*)d_in[4];
    const float* q1   = (const float*)d_in[5];
    const float* k1   = (const float*)d_in[6];
    const float* aw1  = (const float*)d_in[7];
    const float* ab1  = (const float*)d_in[8];
    const float* ow1  = (const float*)d_in[9];
    const float* ob1  = (const float*)d_in[10];
    const float* w_n2 = (const float*)d_in[11];
    const float* w_e2 = (const float*)d_in[12];
    const float* q2   = (const float*)d_in[13];
    const float* k2   = (const float*)d_in[14];
    const float* aw2  = (const float*)d_in[15];
    const float* ab2  = (const float*)d_in[16];
    const float* ow2  = (const float*)d_in[17];
    const float* ob2  = (const float*)d_in[18];
    float* out = (float*)d_out;

    char* ws = (char*)d_ws;
    float*  xpA    = (float*)(ws + OFF_XPA);
    float*  xpB    = (float*)(ws + OFF_XPB);
    float*  sa     = (float*)(ws + OFF_SA);
    float*  sb     = (float*)(ws + OFF_SB);
    float*  vecs   = (float*)(ws + OFF_VECS);
    int*    counts = (int*)(ws + OFF_COUNTS);
    int*    cursor = (int*)(ws + OFF_CURSOR);
    int*    offs   = (int*)(ws + OFF_OFFS);
    int2*   recs   = (int2*)(ws + OFF_RECS);
    float4* att    = (float4*)(ws + OFF_ATT);
    float2* se12   = (float2*)(ws + OFF_SE12);
    int*    order  = (int*)(ws + OFF_ORDER);

    // CSR build (edge_index is layer-invariant)
    hipMemsetAsync(counts, 0, 2 * NN * sizeof(int), stream);  // counts + cursor
    hist_vecs_kernel<<<EE / 256, 256, 0, stream>>>(ei, counts, q1, k1, aw1, w_e1,
                                                   q2, k2, aw2, w_e2, vecs);
    scan_order_kernel<<<1, 1024, 0, stream>>>(counts, offs, order);
    scatter_kernel<<<EE / 256, 256, 0, stream>>>(ei, offs, cursor, attr, vecs,
                                                 ab1, ab2, recs, se12);
    // layer 1
    node_prep_kernel<<<NN / 4, 256, 0, stream>>>(X, w_n1, vecs + 0, vecs + 64, xpA, sa, sb);
    att_kernel<<<EE / 256, 256, 0, stream>>>(ei, se12, sa, sb, att, 0);
    conv_out_kernel<<<NN / 4, 256, 0, stream>>>(xpA, recs, offs, attr, w_e1, att,
                                                ow1, ob1, order, xpB);
    // layer 2
    node_prep_kernel<<<NN / 4, 256, 0, stream>>>(xpB, w_n2, vecs + 144, vecs + 208, xpA, sa, sb);
    att_kernel<<<EE / 256, 256, 0, stream>>>(ei, se12, sa, sb, att, 1);
    conv_out_kernel<<<NN / 4, 256, 0, stream>>>(xpA, recs, offs, attr, w_e2, att,
                                                ow2, ob2, order, out);
}

// Round 6
// 273.963 us; speedup vs baseline: 1.3056x; 1.0407x over previous
//
#include <hip/hip_runtime.h>
#include <math.h>

#define NN 10000
#define BB 4
#define EE 160000
#define CC 64
#define CE 16

// ---- workspace layout (bytes) ----
static constexpr size_t OFF_XPA    = 0;          // float[NN*BB*CC]
static constexpr size_t OFF_XPB    = 10240000;   // float[NN*BB*CC]
static constexpr size_t OFF_SA     = 20480000;   // float[NN*BB]
static constexpr size_t OFF_SB     = 20640000;   // float[NN*BB]
static constexpr size_t OFF_VECS   = 20800000;   // float[288]
static constexpr size_t OFF_COUNTS = 20801280;   // int[NN]
static constexpr size_t OFF_CURSOR = 20841280;   // int[NN]
static constexpr size_t OFF_OFFS   = 20881280;   // int[NN+1]
static constexpr size_t OFF_RECS   = 20921344;   // int2[EE]   (1.28 MB)
static constexpr size_t OFF_ATT    = 22201344;   // float4[EE] (2.56 MB)
static constexpr size_t OFF_SE12   = 24761344;   // float2[EE] (1.28 MB)
static constexpr size_t OFF_ORDER  = 26041344;   // int[NN]    -> total ~26.1 MB

__device__ __forceinline__ float sigmoidf_(float x) {
    // v_rcp_f32 (~1ulp) instead of IEEE divide; validated absmax-identical r1-r5
    return __builtin_amdgcn_rcpf(1.0f + __expf(-x));
}

// broadcast lane `l` (compile-time) of v to all lanes via v_readlane (SGPR path,
// on the VALU pipes -- NOT the LDS pipe)
__device__ __forceinline__ float bcast_(float v, int l) {
    return __uint_as_float(__builtin_amdgcn_readlane(__float_as_uint(v), l));
}

// histogram of dst + (block 0) fold q@aw_q, k@aw_k, w_e@aw_e for both layers
__global__ void hist_vecs_kernel(const int* __restrict__ ei, int* __restrict__ counts,
                                 const float* __restrict__ q1, const float* __restrict__ k1,
                                 const float* __restrict__ aw1, const float* __restrict__ we1,
                                 const float* __restrict__ q2, const float* __restrict__ k2,
                                 const float* __restrict__ aw2, const float* __restrict__ we2,
                                 float* __restrict__ vecs) {
    int e = blockIdx.x * blockDim.x + threadIdx.x;
    if (e < EE) atomicAdd(&counts[ei[EE + e]], 1);
    if (blockIdx.x == 0) {
        int t = threadIdx.x;
        if (t < 64) {
            float a = 0.f, b = 0.f, c = 0.f, d = 0.f;
            for (int j = 0; j < 64; ++j) {
                a = fmaf(q1[t * 64 + j], aw1[j], a);
                b = fmaf(k1[t * 64 + j], aw1[64 + j], b);
                c = fmaf(q2[t * 64 + j], aw2[j], c);
                d = fmaf(k2[t * 64 + j], aw2[64 + j], d);
            }
            vecs[t] = a; vecs[64 + t] = b; vecs[144 + t] = c; vecs[208 + t] = d;
        }
        if (t < 16) {
            float a = 0.f, b = 0.f;
            for (int j = 0; j < 64; ++j) {
                a = fmaf(we1[t * 64 + j], aw1[128 + j], a);
                b = fmaf(we2[t * 64 + j], aw2[128 + j], b);
            }
            vecs[128 + t] = a; vecs[272 + t] = b;
        }
    }
}

// single-block: exclusive scan of counts -> offs, THEN counting-sort nodes by
// degree descending -> order[] (LPT schedule for conv_out). One launch.
__global__ __launch_bounds__(1024) void scan_order_kernel(const int* __restrict__ counts,
                                                          int* __restrict__ offs,
                                                          int* __restrict__ order) {
    __shared__ int hist[1024];
    __shared__ int cur[1024];
    __shared__ int startb[1024];
    __shared__ int wsum[16];
    int t = threadIdx.x;
    hist[t] = 0; cur[t] = 0;
    int lane = t & 63, wid = t >> 6;
    // ---- phase 1: exclusive scan ----
    int v[10];
    int s = 0;
    #pragma unroll
    for (int j = 0; j < 10; ++j) {
        int i = t * 10 + j;
        v[j] = (i < NN) ? counts[i] : 0;
        s += v[j];
    }
    int ps = s;
    #pragma unroll
    for (int off = 1; off < 64; off <<= 1) {
        int u = __shfl_up(ps, off, 64);
        if (lane >= off) ps += u;
    }
    if (lane == 63) wsum[wid] = ps;
    __syncthreads();   // also covers hist/cur zero-init
    int wbase = 0;
    for (int w = 0; w < wid; ++w) wbase += wsum[w];
    int tb = wbase + ps - s;  // exclusive prefix
    #pragma unroll
    for (int j = 0; j < 10; ++j) {
        int i = t * 10 + j;
        if (i < NN) offs[i] = tb;
        tb += v[j];
    }
    if (t == 1023) offs[NN] = tb;
    // ---- phase 2: degree histogram ----
    #pragma unroll
    for (int j = 0; j < 10; ++j) {
        int i = t * 10 + j;
        if (i < NN) {
            int d = v[j] > 1023 ? 1023 : v[j];
            atomicAdd(&hist[d], 1);
        }
    }
    __syncthreads();
    // ---- phase 3: suffix sums (descending bins) ----
    int r = 1023 - t;
    int hv = hist[r];
    int ps2 = hv;
    #pragma unroll
    for (int off = 1; off < 64; off <<= 1) {
        int u = __shfl_up(ps2, off, 64);
        if (lane >= off) ps2 += u;
    }
    if (lane == 63) wsum[wid] = ps2;
    __syncthreads();
    int wb2 = 0;
    for (int w = 0; w < wid; ++w) wb2 += wsum[w];
    startb[r] = wb2 + ps2 - hv;
    __syncthreads();
    // ---- phase 4: scatter node ids ----
    #pragma unroll
    for (int j = 0; j < 10; ++j) {
        int i = t * 10 + j;
        if (i < NN) {
            int d = v[j] > 1023 ? 1023 : v[j];
            int pos = startb[d] + atomicAdd(&cur[d], 1);
            order[pos] = i;
        }
    }
}

// CSR scatter; also fold attr·(w_e@aw_e)+ab per edge for both layers -> se12[e]
__global__ __launch_bounds__(256) void scatter_kernel(
    const int* __restrict__ ei, const int* __restrict__ offs,
    int* __restrict__ cursor, const float* __restrict__ attr,
    const float* __restrict__ vecs, const float* __restrict__ ab1,
    const float* __restrict__ ab2, int2* __restrict__ recs,
    float2* __restrict__ se12) {
    int e = blockIdx.x * blockDim.x + threadIdx.x;
    if (e >= EE) return;
    int s = ei[e], d = ei[EE + e];
    const float4* ap = (const float4*)(attr + (size_t)e * CE);
    float4 a0 = ap[0], a1 = ap[1], a2 = ap[2], a3 = ap[3];
    const float* v1 = vecs + 128;
    const float* v2 = vecs + 272;
    float s1 = ab1[0], s2 = ab2[0];
    s1 = fmaf(a0.x, v1[0], s1);  s1 = fmaf(a0.y, v1[1], s1);
    s1 = fmaf(a0.z, v1[2], s1);  s1 = fmaf(a0.w, v1[3], s1);
    s1 = fmaf(a1.x, v1[4], s1);  s1 = fmaf(a1.y, v1[5], s1);
    s1 = fmaf(a1.z, v1[6], s1);  s1 = fmaf(a1.w, v1[7], s1);
    s1 = fmaf(a2.x, v1[8], s1);  s1 = fmaf(a2.y, v1[9], s1);
    s1 = fmaf(a2.z, v1[10], s1); s1 = fmaf(a2.w, v1[11], s1);
    s1 = fmaf(a3.x, v1[12], s1); s1 = fmaf(a3.y, v1[13], s1);
    s1 = fmaf(a3.z, v1[14], s1); s1 = fmaf(a3.w, v1[15], s1);
    s2 = fmaf(a0.x, v2[0], s2);  s2 = fmaf(a0.y, v2[1], s2);
    s2 = fmaf(a0.z, v2[2], s2);  s2 = fmaf(a0.w, v2[3], s2);
    s2 = fmaf(a1.x, v2[4], s2);  s2 = fmaf(a1.y, v2[5], s2);
    s2 = fmaf(a1.z, v2[6], s2);  s2 = fmaf(a1.w, v2[7], s2);
    s2 = fmaf(a2.x, v2[8], s2);  s2 = fmaf(a2.y, v2[9], s2);
    s2 = fmaf(a2.z, v2[10], s2); s2 = fmaf(a2.w, v2[11], s2);
    s2 = fmaf(a3.x, v2[12], s2); s2 = fmaf(a3.y, v2[13], s2);
    s2 = fmaf(a3.z, v2[14], s2); s2 = fmaf(a3.w, v2[15], s2);
    int p = atomicAdd(&cursor[d], 1);
    recs[offs[d] + p] = make_int2(s, e);
    se12[e] = make_float2(s1, s2);
}

// xp = x @ w_n ; sa = xp@qa ; sb = xp@ka.  One wave per node, 4 nodes/block.
// ZERO LDS, ZERO barrier: wave loads its node row as one float4/lane
// (lane (b<<4)|q holds channels 4q..4q+3 of batch b); x[b][ci] broadcast via
// v_readlane at compile-time lane index; w_n column read coalesced (L1-hot 16KB).
__global__ __launch_bounds__(256) void node_prep_kernel(
    const float* __restrict__ x, const float* __restrict__ w_n,
    const float* __restrict__ qa, const float* __restrict__ ka,
    float* __restrict__ xp, float* __restrict__ sa, float* __restrict__ sb) {
    int t = threadIdx.x, wave = t >> 6, lane = t & 63;
    int node = blockIdx.x * 4 + wave;
    float4 xv = ((const float4*)(x + (size_t)node * BB * CC))[lane];
    float acc0 = 0.f, acc1 = 0.f, acc2 = 0.f, acc3 = 0.f;
    #pragma unroll
    for (int ci = 0; ci < 64; ++ci) {
        float w = w_n[ci * 64 + lane];                 // coalesced column of w_n
        // component pick is compile-time (full unroll)
        float c0 = ((ci & 3) == 0) ? xv.x : ((ci & 3) == 1) ? xv.y
                 : ((ci & 3) == 2) ? xv.z : xv.w;
        int src = ci >> 2;
        acc0 = fmaf(bcast_(c0, (0 << 4) | src), w, acc0);
        acc1 = fmaf(bcast_(c0, (1 << 4) | src), w, acc1);
        acc2 = fmaf(bcast_(c0, (2 << 4) | src), w, acc2);
        acc3 = fmaf(bcast_(c0, (3 << 4) | src), w, acc3);
    }
    size_t obase = (size_t)node * BB * CC + lane;
    xp[obase] = acc0;
    xp[obase + 64] = acc1;
    xp[obase + 128] = acc2;
    xp[obase + 192] = acc3;
    float qv = qa[lane], kv = ka[lane];
    float ra0 = acc0 * qv, ra1 = acc1 * qv, ra2 = acc2 * qv, ra3 = acc3 * qv;
    float rb0 = acc0 * kv, rb1 = acc1 * kv, rb2 = acc2 * kv, rb3 = acc3 * kv;
    #pragma unroll
    for (int off = 32; off >= 1; off >>= 1) {
        ra0 += __shfl_xor(ra0, off, 64); ra1 += __shfl_xor(ra1, off, 64);
        ra2 += __shfl_xor(ra2, off, 64); ra3 += __shfl_xor(ra3, off, 64);
        rb0 += __shfl_xor(rb0, off, 64); rb1 += __shfl_xor(rb1, off, 64);
        rb2 += __shfl_xor(rb2, off, 64); rb3 += __shfl_xor(rb3, off, 64);
    }
    if (lane == 0) {
        sa[node * BB + 0] = ra0; sa[node * BB + 1] = ra1;
        sa[node * BB + 2] = ra2; sa[node * BB + 3] = ra3;
        sb[node * BB + 0] = rb0; sb[node * BB + 1] = rb1;
        sb[node * BB + 2] = rb2; sb[node * BB + 3] = rb3;
    }
}

// per-edge attention scalar: att4[e] = sigmoid(sa[src] + sb[dst] + se12[e])
__global__ __launch_bounds__(256) void att_kernel(
    const int* __restrict__ ei, const float2* __restrict__ se12,
    const float* __restrict__ sa, const float* __restrict__ sb,
    float4* __restrict__ att, int sel) {
    int e = blockIdx.x * blockDim.x + threadIdx.x;
    if (e >= EE) return;
    int s = ei[e], d = ei[EE + e];
    float2 se2 = se12[e];
    float se = sel ? se2.y : se2.x;
    float4 sas = *(const float4*)(sa + (size_t)s * BB);
    float4 sbn = *(const float4*)(sb + (size_t)d * BB);
    float4 r;
    r.x = sigmoidf_(sas.x + sbn.x + se);
    r.y = sigmoidf_(sas.y + sbn.y + se);
    r.z = sigmoidf_(sas.z + sbn.z + se);
    r.w = sigmoidf_(sas.w + sbn.w + se);
    att[e] = r;
}

// ---- conv_out: depth-2 pipelined edge loop + readlane epilogue (zero LDS) ----
// Slot loads: att (precomputed, 1 b128) + attr (4 b128) + xp row (4 b32) = 9
// VMEM in flight per slot; compute slot A while slot B's loads are outstanding.
#define CLOAD(R_, P) {                                                        \
    P##at = att[(R_).y];                                                      \
    const float4* ap_ = (const float4*)(attr + (size_t)(R_).y * CE);          \
    P##a0 = ap_[0]; P##a1 = ap_[1]; P##a2 = ap_[2]; P##a3 = ap_[3];           \
    const float* xs_ = xp + (size_t)(R_).x * (BB * CC) + lane;                \
    P##x0 = xs_[0]; P##x1 = xs_[64]; P##x2 = xs_[128]; P##x3 = xs_[192]; }

#define CCOMP(P) {                                                            \
    float g_ = 0.f;                                                           \
    g_ = fmaf(P##a0.x, wec[0], g_);  g_ = fmaf(P##a0.y, wec[1], g_);          \
    g_ = fmaf(P##a0.z, wec[2], g_);  g_ = fmaf(P##a0.w, wec[3], g_);          \
    g_ = fmaf(P##a1.x, wec[4], g_);  g_ = fmaf(P##a1.y, wec[5], g_);          \
    g_ = fmaf(P##a1.z, wec[6], g_);  g_ = fmaf(P##a1.w, wec[7], g_);          \
    g_ = fmaf(P##a2.x, wec[8], g_);  g_ = fmaf(P##a2.y, wec[9], g_);          \
    g_ = fmaf(P##a2.z, wec[10], g_); g_ = fmaf(P##a2.w, wec[11], g_);         \
    g_ = fmaf(P##a3.x, wec[12], g_); g_ = fmaf(P##a3.y, wec[13], g_);         \
    g_ = fmaf(P##a3.z, wec[14], g_); g_ = fmaf(P##a3.w, wec[15], g_);         \
    g_ = sigmoidf_(g_);                                                       \
    m0 = fmaxf(m0, P##at.x * P##x0 * g_);                                     \
    m1 = fmaxf(m1, P##at.y * P##x1 * g_);                                     \
    m2 = fmaxf(m2, P##at.z * P##x2 * g_);                                     \
    m3 = fmaxf(m3, P##at.w * P##x3 * g_); }

__global__ __launch_bounds__(256) void conv_out_kernel(
    const float* __restrict__ xp,      // [NN,BB,CC]
    const int2* __restrict__ recs,     // [EE] {src, e}
    const int* __restrict__ offs,      // [NN+1]
    const float* __restrict__ attr,    // [EE,CE]
    const float* __restrict__ w_e,     // [CE,CC]
    const float4* __restrict__ att,    // [EE]
    const float* __restrict__ ow,      // [2*CC,CC]
    const float* __restrict__ ob,      // [CC]
    const int* __restrict__ order,     // [NN] degree-descending node ids
    float* __restrict__ out) {         // [NN,BB,CC]
    int t = threadIdx.x;
    int wave = t >> 6, lane = t & 63;
    int node = order[blockIdx.x * 4 + wave];

    float wec[CE];
    #pragma unroll
    for (int j = 0; j < CE; ++j) wec[j] = w_e[j * CC + lane];

    const float* xn = xp + (size_t)node * BB * CC + lane;
    float xn0 = xn[0], xn1 = xn[64], xn2 = xn[128], xn3 = xn[192];

    int o0 = offs[node], o1 = offs[node + 1];
    int n = o1 - o0;
    const int2* rp = recs + o0;
    float m0 = -INFINITY, m1 = -INFINITY, m2 = -INFINITY, m3 = -INFINITY;

    float4 Aat, Aa0, Aa1, Aa2, Aa3; float Ax0, Ax1, Ax2, Ax3;
    float4 Bat, Ba0, Ba1, Ba2, Ba3; float Bx0, Bx1, Bx2, Bx3;
    int2 rA = make_int2(0, 0), rB = rA;
    if (n > 0) { rA = rp[0]; CLOAD(rA, A); }
    if (n > 1) { rB = rp[1]; CLOAD(rB, B); }
    int i = 0;
    #pragma unroll 1
    for (; i + 2 < n; i += 2) {
        int2 rA2 = rp[i + 2];
        int2 rB2 = (i + 3 < n) ? rp[i + 3] : rA2;
        CCOMP(A);
        rA = rA2; CLOAD(rA, A);
        CCOMP(B);
        rB = rB2; CLOAD(rB, B);
    }
    if (i < n)     CCOMP(A);
    if (i + 1 < n) CCOMP(B);
    // empty segments -> 0
    m0 = (m0 == -INFINITY) ? 0.f : m0;
    m1 = (m1 == -INFINITY) ? 0.f : m1;
    m2 = (m2 == -INFINITY) ? 0.f : m2;
    m3 = (m3 == -INFINITY) ? 0.f : m3;

    // ---- epilogue: out = xp + concat([xp, aggr]) @ ow + ob, leaky_relu ----
    // lane = output channel; per ci: 2 coalesced ow loads + 8 readlane + 8 FMA
    float o0f = 0.f, o1f = 0.f, o2f = 0.f, o3f = 0.f;
    #pragma unroll
    for (int ci = 0; ci < 64; ++ci) {
        float wa = ow[ci * 64 + lane];         // coalesced, L1/L2-resident
        float wb = ow[(64 + ci) * 64 + lane];
        o0f = fmaf(bcast_(xn0, ci), wa, o0f);
        o1f = fmaf(bcast_(xn1, ci), wa, o1f);
        o2f = fmaf(bcast_(xn2, ci), wa, o2f);
        o3f = fmaf(bcast_(xn3, ci), wa, o3f);
        o0f = fmaf(bcast_(m0, ci), wb, o0f);
        o1f = fmaf(bcast_(m1, ci), wb, o1f);
        o2f = fmaf(bcast_(m2, ci), wb, o2f);
        o3f = fmaf(bcast_(m3, ci), wb, o3f);
    }
    float obv = ob[lane];
    float r0 = xn0 + o0f + obv;
    float r1 = xn1 + o1f + obv;
    float r2 = xn2 + o2f + obv;
    float r3 = xn3 + o3f + obv;
    r0 = (r0 > 0.f) ? r0 : 0.01f * r0;
    r1 = (r1 > 0.f) ? r1 : 0.01f * r1;
    r2 = (r2 > 0.f) ? r2 : 0.01f * r2;
    r3 = (r3 > 0.f) ? r3 : 0.01f * r3;
    float* op = out + (size_t)node * BB * CC + lane;
    op[0] = r0; op[64] = r1; op[128] = r2; op[192] = r3;
}

extern "C" void kernel_launch(void* const* d_in, const int* in_sizes, int n_in,
                              void* d_out, int out_size, void* d_ws, size_t ws_size,
                              hipStream_t stream) {
    const float* X    = (const float*)d_in[0];
    const int*   ei   = (const int*)d_in[1];
    const float* attr = (const float*)d_in[2];
    const float* w_n1 = (const float*)d_in[3];
    const float* w_e1 = (const float*)d_in[4];
    const float* q1   = (const float*)d_in[5];
    const float* k1   = (const float*)d_in[6];
    const float* aw1  = (const float*)d_in[7];
    const float* ab1  = (const float*)d_in[8];
    const float* ow1  = (const float*)d_in[9];
    const float* ob1  = (const float*)d_in[10];
    const float* w_n2 = (const float*)d_in[11];
    const float* w_e2 = (const float*)d_in[12];
    const float* q2   = (const float*)d_in[13];
    const float* k2   = (const float*)d_in[14];
    const float* aw2  = (const float*)d_in[15];
    const float* ab2  = (const float*)d_in[16];
    const float* ow2  = (const float*)d_in[17];
    const float* ob2  = (const float*)d_in[18];
    float* out = (float*)d_out;

    char* ws = (char*)d_ws;
    float*  xpA    = (float*)(ws + OFF_XPA);
    float*  xpB    = (float*)(ws + OFF_XPB);
    float*  sa     = (float*)(ws + OFF_SA);
    float*  sb     = (float*)(ws + OFF_SB);
    float*  vecs   = (float*)(ws + OFF_VECS);
    int*    counts = (int*)(ws + OFF_COUNTS);
    int*    cursor = (int*)(ws + OFF_CURSOR);
    int*    offs   = (int*)(ws + OFF_OFFS);
    int2*   recs   = (int2*)(ws + OFF_RECS);
    float4* att    = (float4*)(ws + OFF_ATT);
    float2* se12   = (float2*)(ws + OFF_SE12);
    int*    order  = (int*)(ws + OFF_ORDER);

    // CSR build (edge_index is layer-invariant)
    hipMemsetAsync(counts, 0, 2 * NN * sizeof(int), stream);  // counts + cursor
    hist_vecs_kernel<<<EE / 256, 256, 0, stream>>>(ei, counts, q1, k1, aw1, w_e1,
                                                   q2, k2, aw2, w_e2, vecs);
    scan_order_kernel<<<1, 1024, 0, stream>>>(counts, offs, order);
    scatter_kernel<<<EE / 256, 256, 0, stream>>>(ei, offs, cursor, attr, vecs,
                                                 ab1, ab2, recs, se12);
    // layer 1
    node_prep_kernel<<<NN / 4, 256, 0, stream>>>(X, w_n1, vecs + 0, vecs + 64, xpA, sa, sb);
    att_kernel<<<EE / 256, 256, 0, stream>>>(ei, se12, sa, sb, att, 0);
    conv_out_kernel<<<NN / 4, 256, 0, stream>>>(xpA, recs, offs, attr, w_e1, att,
                                                ow1, ob1, order, xpB);
    // layer 2
    node_prep_kernel<<<NN / 4, 256, 0, stream>>>(xpB, w_n2, vecs + 144, vecs + 208, xpA, sa, sb);
    att_kernel<<<EE / 256, 256, 0, stream>>>(ei, se12, sa, sb, att, 1);
    conv_out_kernel<<<NN / 4, 256, 0, stream>>>(xpA, recs, offs, attr, w_e2, att,
                                                ow2, ob2, order, out);
}